// Round 1
// baseline (1347.423 us; speedup 1.0000x reference)
//
#include <hip/hip_runtime.h>

#define BB 65536
#define TT 20
#define HH 10
#define NG 40   // 4*H

__device__ __forceinline__ float sigmoid_f(float x) {
    float t = __builtin_amdgcn_exp2f(-1.44269504f * x);   // 2^(-x*log2e) = e^-x
    return __builtin_amdgcn_rcpf(1.0f + t);
}

__device__ __forceinline__ float tanh_f(float x) {
    float t = __builtin_amdgcn_exp2f(2.88539008f * x);    // e^(2x)
    return 1.0f - 2.0f * __builtin_amdgcn_rcpf(t + 1.0f); // (t-1)/(t+1)
}

// One LSTM cell step. Gate order (PyTorch): i, f, g, o.
template<int IN>
__device__ __forceinline__ void lstm_cell(const float* xin, float* h, float* c,
    const float* __restrict__ wih, const float* __restrict__ whh,
    const float* __restrict__ bih, const float* __restrict__ bhh)
{
    float g[NG];
#pragma unroll
    for (int gi = 0; gi < NG; ++gi) {
        float acc = bih[gi] + bhh[gi];
#pragma unroll
        for (int k = 0; k < IN; ++k) acc = fmaf(wih[gi * IN + k], xin[k], acc);
#pragma unroll
        for (int j = 0; j < HH; ++j) acc = fmaf(whh[gi * HH + j], h[j], acc);
        g[gi] = acc;
    }
#pragma unroll
    for (int j = 0; j < HH; ++j) {
        float cv = sigmoid_f(g[HH + j]) * c[j] + sigmoid_f(g[j]) * tanh_f(g[2 * HH + j]);
        c[j] = cv;
        h[j] = sigmoid_f(g[3 * HH + j]) * tanh_f(cv);
    }
}

__device__ __forceinline__ void build_x(int b, int t,
    const int* __restrict__ e, const float* __restrict__ f,
    const float* __restrict__ emb, const float* __restrict__ fw,
    const float* __restrict__ fb, float* x, float* mask)
{
    int idx = b * TT + t;
    int ei  = e[idx];
    float f0 = f[idx * 3 + 0];
    float f1 = f[idx * 3 + 1];
    float f2 = f[idx * 3 + 2];
    x[0] = emb[ei * 3 + 0];
    x[1] = emb[ei * 3 + 1];
    x[2] = emb[ei * 3 + 2];
    x[3] = fmaf(fw[0], f0, fmaf(fw[1], f1, fmaf(fw[2], f2, fb[0])));
    x[4] = fmaf(fw[3], f0, fmaf(fw[4], f1, fmaf(fw[5], f2, fb[1])));
    x[5] = fmaf(fw[6], f0, fmaf(fw[7], f1, fmaf(fw[8], f2, fb[2])));
    *mask = (f1 != 0.0f) ? 1.0f : 0.0f;
}

__global__ __launch_bounds__(256)
void bilstm_fused_kernel(
    const int*   __restrict__ e,    const float* __restrict__ f,
    const float* __restrict__ emb,  const float* __restrict__ fw,
    const float* __restrict__ fb,
    const float* __restrict__ wih0, const float* __restrict__ whh0,
    const float* __restrict__ bih0, const float* __restrict__ bhh0,
    const float* __restrict__ wih0r,const float* __restrict__ whh0r,
    const float* __restrict__ bih0r,const float* __restrict__ bhh0r,
    const float* __restrict__ wih1r,const float* __restrict__ whh1r,
    const float* __restrict__ bih1r,const float* __restrict__ bhh1r,
    float* __restrict__ out)
{
    int b = blockIdx.x * blockDim.x + threadIdx.x;
    if (b >= BB) return;

    // Per-thread storage of layer-0 forward hiddens (goes to scratch; rolled
    // t-loops keep code size small; 800B/thread round-trips through L2/L3).
    float hf0[TT][HH];

    // ---------- Phase 1: layer-0 forward LSTM ----------
    {
        float h[HH], c[HH];
#pragma unroll
        for (int j = 0; j < HH; ++j) { h[j] = 0.0f; c[j] = 0.0f; }
#pragma unroll 1
        for (int t = 0; t < TT; ++t) {
            float x[6], mask;
            build_x(b, t, e, f, emb, fw, fb, x, &mask);
            lstm_cell<6>(x, h, c, wih0, whh0, bih0, bhh0);
#pragma unroll
            for (int j = 0; j < HH; ++j) hf0[t][j] = h[j];
        }
    }

    // ---------- Phase 2: fused layer-0 backward + layer-1 backward ----------
    // (layer-1 forward direction is dead: output only uses channel 19 = bwd unit 9)
    {
        float hb[HH], cb[HH], h1[HH], c1[HH];
#pragma unroll
        for (int j = 0; j < HH; ++j) { hb[j] = 0.0f; cb[j] = 0.0f; h1[j] = 0.0f; c1[j] = 0.0f; }
        float total = 0.0f;
#pragma unroll 1
        for (int t = TT - 1; t >= 0; --t) {
            float x[6], mask;
            build_x(b, t, e, f, emb, fw, fb, x, &mask);

            // layer-0 backward cell -> hb = hb0[t]
            lstm_cell<6>(x, hb, cb, wih0r, whh0r, bih0r, bhh0r);

            // layer-1 backward cell, input = concat(hf0[t], hb0[t])
            float x1[2 * HH];
#pragma unroll
            for (int j = 0; j < HH; ++j) { x1[j] = hf0[t][j]; x1[HH + j] = hb[j]; }
            lstm_cell<2 * HH>(x1, h1, c1, wih1r, whh1r, bih1r, bhh1r);

            float ip = h1[HH - 1] * mask;
            ip = ip > 0.0f ? ip : 0.0f;
            out[BB + b * TT + t] = ip;
            total += ip;
        }
        out[b] = total;
    }
}

extern "C" void kernel_launch(void* const* d_in, const int* in_sizes, int n_in,
                              void* d_out, int out_size, void* d_ws, size_t ws_size,
                              hipStream_t stream) {
    const int*   e     = (const int*)  d_in[0];
    const float* f     = (const float*)d_in[1];
    const float* emb   = (const float*)d_in[2];
    const float* fw    = (const float*)d_in[3];
    const float* fb    = (const float*)d_in[4];
    const float* wih0  = (const float*)d_in[5];
    const float* whh0  = (const float*)d_in[6];
    const float* bih0  = (const float*)d_in[7];
    const float* bhh0  = (const float*)d_in[8];
    const float* wih0r = (const float*)d_in[9];
    const float* whh0r = (const float*)d_in[10];
    const float* bih0r = (const float*)d_in[11];
    const float* bhh0r = (const float*)d_in[12];
    // d_in[13..16] = layer-1 forward weights: dead code, never read.
    const float* wih1r = (const float*)d_in[17];
    const float* whh1r = (const float*)d_in[18];
    const float* bih1r = (const float*)d_in[19];
    const float* bhh1r = (const float*)d_in[20];

    float* out = (float*)d_out;

    dim3 grid(BB / 256), block(256);
    hipLaunchKernelGGL(bilstm_fused_kernel, grid, block, 0, stream,
                       e, f, emb, fw, fb,
                       wih0, whh0, bih0, bhh0,
                       wih0r, whh0r, bih0r, bhh0r,
                       wih1r, whh1r, bih1r, bhh1r,
                       out);
}

// Round 2
// 285.606 us; speedup vs baseline: 4.7178x; 4.7178x over previous
//
#include <hip/hip_runtime.h>

#define BB 65536
#define TT 20
#define HH 10
#define EPB 64          // elements per block (one per lane)
#define NW  4           // waves per block: wave w = gate type w (i,f,g,o)

__device__ __forceinline__ float sigmoid_f(float x) {
    float t = __builtin_amdgcn_exp2f(-1.44269504f * x);   // e^-x
    return __builtin_amdgcn_rcpf(1.0f + t);
}
__device__ __forceinline__ float tanh_f(float x) {
    float t = __builtin_amdgcn_exp2f(2.88539008f * x);    // e^(2x)
    return 1.0f - 2.0f * __builtin_amdgcn_rcpf(t + 1.0f);
}

// bf16 pair pack/unpack (round-to-nearest-ish)
__device__ __forceinline__ unsigned int pk_bf16(float a, float b) {
    unsigned int ua = (__float_as_uint(a) + 0x8000u) >> 16;
    unsigned int ub = (__float_as_uint(b) + 0x8000u) & 0xFFFF0000u;
    return ua | ub;
}
__device__ __forceinline__ float unpk_lo(unsigned int u) { return __uint_as_float(u << 16); }
__device__ __forceinline__ float unpk_hi(unsigned int u) { return __uint_as_float(u & 0xFFFF0000u); }

struct LdsBuf {
    float        hf0[TT][HH][EPB];   // 51200 B  layer-0 fwd hidden seq (fp32)
    unsigned int x6[TT][3][EPB];     // 15360 B  x (6 ch) as bf16 pairs
    unsigned char msk[TT][EPB];      //  1280 B  mask bits
    float        ex[4 * HH][EPB];    // 10240 B  gate exchange (i|f|g|o x 10 units)
};                                    // total 78080 B -> 2 blocks/CU

__global__ __launch_bounds__(256, 2)
void bilstm_gate_split_kernel(
    const int*   __restrict__ e,    const float* __restrict__ f,
    const float* __restrict__ emb,  const float* __restrict__ fw,
    const float* __restrict__ fb,
    const float* __restrict__ wih0, const float* __restrict__ whh0,
    const float* __restrict__ bih0, const float* __restrict__ bhh0,
    const float* __restrict__ wih0r,const float* __restrict__ whh0r,
    const float* __restrict__ bih0r,const float* __restrict__ bhh0r,
    const float* __restrict__ wih1r,const float* __restrict__ whh1r,
    const float* __restrict__ bih1r,const float* __restrict__ bhh1r,
    float* __restrict__ out)
{
    __shared__ LdsBuf lds;

    const int tid  = threadIdx.x;
    const int lane = tid & 63;
    const int wu   = __builtin_amdgcn_readfirstlane(tid >> 6);  // gate-type role, SGPR
    const int b0   = blockIdx.x * EPB;

    // ---------------- Stage inputs (coalesced) ----------------
    {
        float* traw = &lds.hf0[0][0][0];            // reuse hf0 area for raw f slice
        int*   eraw = (int*)&lds.ex[0][0];          // reuse ex area for e slice
        for (int i = tid; i < EPB * TT * 3; i += 256) traw[i] = f[b0 * TT * 3 + i];
        for (int i = tid; i < EPB * TT; i += 256)     eraw[i] = e[b0 * TT + i];
        __syncthreads();
        float fw0 = fw[0], fw1 = fw[1], fw2 = fw[2];
        float fw3 = fw[3], fw4 = fw[4], fw5 = fw[5];
        float fw6 = fw[6], fw7 = fw[7], fw8 = fw[8];
        float fb0 = fb[0], fb1 = fb[1], fb2 = fb[2];
        for (int p = tid; p < EPB * TT; p += 256) {
            int elem = p / TT, t = p - elem * TT;
            float f0 = traw[p * 3], f1 = traw[p * 3 + 1], f2 = traw[p * 3 + 2];
            int ei = eraw[p] * 3;
            float x0 = emb[ei], x1 = emb[ei + 1], x2 = emb[ei + 2];
            float x3 = fmaf(fw0, f0, fmaf(fw1, f1, fmaf(fw2, f2, fb0)));
            float x4 = fmaf(fw3, f0, fmaf(fw4, f1, fmaf(fw5, f2, fb1)));
            float x5 = fmaf(fw6, f0, fmaf(fw7, f1, fmaf(fw8, f2, fb2)));
            unsigned int u0 = pk_bf16(x0, x1), u1 = pk_bf16(x2, x3), u2 = pk_bf16(x4, x5);
            lds.msk[t][elem] = (f1 != 0.0f) ? 1 : 0;
            // defer x6 writes until after barrier? no: x6 doesn't alias traw/eraw areas.
            lds.x6[t][0][elem] = u0;
            lds.x6[t][1][elem] = u1;
            lds.x6[t][2][elem] = u2;
        }
        __syncthreads();
    }

    // Per-role weight bases (uniform -> scalar loads)
    const float* Wi0  = wih0  + wu * HH * 6;
    const float* Wh0  = whh0  + wu * HH * HH;
    const float* Wi0r = wih0r + wu * HH * 6;
    const float* Wh0r = whh0r + wu * HH * HH;
    const float* Wi1  = wih1r + wu * HH * 20;
    const float* Wh1  = whh1r + wu * HH * HH;
    float bs0[HH], bs0r[HH], bs1[HH];
#pragma unroll
    for (int u = 0; u < HH; ++u) {
        bs0[u]  = bih0 [wu * HH + u] + bhh0 [wu * HH + u];
        bs0r[u] = bih0r[wu * HH + u] + bhh0r[wu * HH + u];
        bs1[u]  = bih1r[wu * HH + u] + bhh1r[wu * HH + u];
    }

    // ---------------- Phase 1: layer-0 forward ----------------
    {
        float h[HH], c[HH];
#pragma unroll
        for (int j = 0; j < HH; ++j) { h[j] = 0.0f; c[j] = 0.0f; }
#pragma unroll 1
        for (int t = 0; t < TT; ++t) {
            unsigned int u0 = lds.x6[t][0][lane], u1 = lds.x6[t][1][lane], u2 = lds.x6[t][2][lane];
            float x[6] = { unpk_lo(u0), unpk_hi(u0), unpk_lo(u1), unpk_hi(u1), unpk_lo(u2), unpk_hi(u2) };
            float a[HH];
#pragma unroll
            for (int u = 0; u < HH; ++u) {
                float acc = bs0[u];
#pragma unroll
                for (int k = 0; k < 6; ++k)  acc = fmaf(Wi0[u * 6 + k], x[k], acc);
#pragma unroll
                for (int j = 0; j < HH; ++j) acc = fmaf(Wh0[u * HH + j], h[j], acc);
                a[u] = acc;
            }
            if (wu == 2) {
#pragma unroll
                for (int u = 0; u < HH; ++u) lds.ex[2 * HH + u][lane] = tanh_f(a[u]);
            } else {
#pragma unroll
                for (int u = 0; u < HH; ++u) lds.ex[wu * HH + u][lane] = sigmoid_f(a[u]);
            }
            __syncthreads();
#pragma unroll
            for (int u = 0; u < HH; ++u) {
                float iv = lds.ex[u][lane],          fv = lds.ex[HH + u][lane];
                float gv = lds.ex[2 * HH + u][lane], ov = lds.ex[3 * HH + u][lane];
                c[u] = fmaf(fv, c[u], iv * gv);
                h[u] = ov * tanh_f(c[u]);
            }
#pragma unroll
            for (int u = 0; u < HH; ++u)             // distribute hf0 writes across waves
                if ((u & 3) == wu) lds.hf0[t][u][lane] = h[u];
            __syncthreads();
        }
    }

    // ------- Phase 2: fused layer-0 backward + layer-1 backward -------
    {
        float hb[HH], cb[HH], h1[HH], c1[HH];
#pragma unroll
        for (int j = 0; j < HH; ++j) { hb[j] = 0.0f; cb[j] = 0.0f; h1[j] = 0.0f; c1[j] = 0.0f; }
        float tot = 0.0f;
#pragma unroll 1
        for (int t = TT - 1; t >= 0; --t) {
            // ---- cell A: layer-0 backward ----
            unsigned int u0 = lds.x6[t][0][lane], u1 = lds.x6[t][1][lane], u2 = lds.x6[t][2][lane];
            float x[6] = { unpk_lo(u0), unpk_hi(u0), unpk_lo(u1), unpk_hi(u1), unpk_lo(u2), unpk_hi(u2) };
            float a[HH];
#pragma unroll
            for (int u = 0; u < HH; ++u) {
                float acc = bs0r[u];
#pragma unroll
                for (int k = 0; k < 6; ++k)  acc = fmaf(Wi0r[u * 6 + k], x[k], acc);
#pragma unroll
                for (int j = 0; j < HH; ++j) acc = fmaf(Wh0r[u * HH + j], hb[j], acc);
                a[u] = acc;
            }
            if (wu == 2) {
#pragma unroll
                for (int u = 0; u < HH; ++u) lds.ex[2 * HH + u][lane] = tanh_f(a[u]);
            } else {
#pragma unroll
                for (int u = 0; u < HH; ++u) lds.ex[wu * HH + u][lane] = sigmoid_f(a[u]);
            }
            __syncthreads();
#pragma unroll
            for (int u = 0; u < HH; ++u) {
                float iv = lds.ex[u][lane],          fv = lds.ex[HH + u][lane];
                float gv = lds.ex[2 * HH + u][lane], ov = lds.ex[3 * HH + u][lane];
                cb[u] = fmaf(fv, cb[u], iv * gv);
                hb[u] = ov * tanh_f(cb[u]);
            }
            __syncthreads();   // ex consumed; safe to overwrite in cell B

            // ---- cell B: layer-1 backward, input = [hf0[t], hb] ----
            float xh[HH];
#pragma unroll
            for (int u = 0; u < HH; ++u) xh[u] = lds.hf0[t][u][lane];
#pragma unroll
            for (int u = 0; u < HH; ++u) {
                float acc = bs1[u];
#pragma unroll
                for (int k = 0; k < HH; ++k) acc = fmaf(Wi1[u * 20 + k], xh[k], acc);
#pragma unroll
                for (int k = 0; k < HH; ++k) acc = fmaf(Wi1[u * 20 + HH + k], hb[k], acc);
#pragma unroll
                for (int j = 0; j < HH; ++j) acc = fmaf(Wh1[u * HH + j], h1[j], acc);
                a[u] = acc;
            }
            if (wu == 2) {
#pragma unroll
                for (int u = 0; u < HH; ++u) lds.ex[2 * HH + u][lane] = tanh_f(a[u]);
            } else {
#pragma unroll
                for (int u = 0; u < HH; ++u) lds.ex[wu * HH + u][lane] = sigmoid_f(a[u]);
            }
            __syncthreads();
#pragma unroll
            for (int u = 0; u < HH; ++u) {
                float iv = lds.ex[u][lane],          fv = lds.ex[HH + u][lane];
                float gv = lds.ex[2 * HH + u][lane], ov = lds.ex[3 * HH + u][lane];
                c1[u] = fmaf(fv, c1[u], iv * gv);
                h1[u] = ov * tanh_f(c1[u]);
            }
            if (wu == 0) {
                float m  = lds.msk[t][lane] ? 1.0f : 0.0f;
                float ip = fmaxf(h1[HH - 1] * m, 0.0f);
                out[BB + (b0 + lane) * TT + t] = ip;
                tot += ip;
            }
            __syncthreads();   // protect ex before next t's cell A writes
        }
        if (wu == 0) out[b0 + lane] = tot;
    }
}

extern "C" void kernel_launch(void* const* d_in, const int* in_sizes, int n_in,
                              void* d_out, int out_size, void* d_ws, size_t ws_size,
                              hipStream_t stream) {
    const int*   e     = (const int*)  d_in[0];
    const float* f     = (const float*)d_in[1];
    const float* emb   = (const float*)d_in[2];
    const float* fw    = (const float*)d_in[3];
    const float* fb    = (const float*)d_in[4];
    const float* wih0  = (const float*)d_in[5];
    const float* whh0  = (const float*)d_in[6];
    const float* bih0  = (const float*)d_in[7];
    const float* bhh0  = (const float*)d_in[8];
    const float* wih0r = (const float*)d_in[9];
    const float* whh0r = (const float*)d_in[10];
    const float* bih0r = (const float*)d_in[11];
    const float* bhh0r = (const float*)d_in[12];
    // d_in[13..16] = layer-1 forward weights: dead code (output uses only bwd unit 9)
    const float* wih1r = (const float*)d_in[17];
    const float* whh1r = (const float*)d_in[18];
    const float* bih1r = (const float*)d_in[19];
    const float* bhh1r = (const float*)d_in[20];

    float* out = (float*)d_out;

    dim3 grid(BB / EPB), block(NW * 64);
    hipLaunchKernelGGL(bilstm_gate_split_kernel, grid, block, 0, stream,
                       e, f, emb, fw, fb,
                       wih0, whh0, bih0, bhh0,
                       wih0r, whh0r, bih0r, bhh0r,
                       wih1r, whh1r, bih1r, bhh1r,
                       out);
}